// Round 9
// baseline (68.389 us; speedup 1.0000x reference)
//
#include <hip/hip_runtime.h>

#define NSEQ 32
#define NH 32
#define NKV 8
#define GRP 4
#define HD 128
#define BS 16
#define MAXCTX 2048
#define BPS 128
#define CHUNK 256
#define NSPLIT (MAXCTX / CHUNK)   // 8
#define SCALE 0.08838834764831845f
#define NEGINF -3.0e38f

__device__ __forceinline__ float dot8(float4 qa, float4 qb, float4 ka, float4 kb) {
  float r = qa.x * ka.x;
  r = fmaf(qa.y, ka.y, r);
  r = fmaf(qa.z, ka.z, r);
  r = fmaf(qa.w, ka.w, r);
  r = fmaf(qb.x, kb.x, r);
  r = fmaf(qb.y, kb.y, r);
  r = fmaf(qb.z, kb.z, r);
  r = fmaf(qb.w, kb.w, r);
  return r;
}

__device__ __forceinline__ float red16(float x) {
  x += __shfl_xor(x, 1);
  x += __shfl_xor(x, 2);
  x += __shfl_xor(x, 4);
  x += __shfl_xor(x, 8);
  return x;
}

__device__ __forceinline__ void red_sub(float4& v) {
  v.x += __shfl_xor(v.x, 16); v.y += __shfl_xor(v.y, 16);
  v.z += __shfl_xor(v.z, 16); v.w += __shfl_xor(v.w, 16);
  v.x += __shfl_xor(v.x, 32); v.y += __shfl_xor(v.y, 32);
  v.z += __shfl_xor(v.z, 32); v.w += __shfl_xor(v.w, 32);
}

// One workgroup per (kv-head, dense-active-split). FUSED single pass:
// per 4-token group load K+V together, online-softmax (rescale only when
// the wave max grows), accumulate P*V directly. Per-wave (m,l,acc) merged
// via LSE in the epilogue together with the new token.
extern "C" __global__ __launch_bounds__(256, 4)
void paged_split(const float* __restrict__ q,
                 const float* __restrict__ k_new,
                 const float* __restrict__ v_new,
                 const float* __restrict__ k_cache,
                 const float* __restrict__ v_cache,
                 const float* __restrict__ cos_cache,
                 const float* __restrict__ sin_cache,
                 const int* __restrict__ block_tables,
                 const int* __restrict__ context_lens,
                 float* __restrict__ accW,
                 float2* __restrict__ mlW)
{
  const int kv = blockIdx.x;   // 0..7
  // ---- dense remap: blockIdx.y -> (s, sp), wave-uniform scan ----
  int s = -1, sp = blockIdx.y;
  for (int i = 0; i < NSEQ; ++i) {
    int ns = (context_lens[i] + CHUNK - 1) / CHUNK;
    if (sp < ns) { s = i; break; }
    sp -= ns;
  }
  if (s < 0) return;

  const int ctx = context_lens[s];
  const int t0  = sp * CHUNK;
  const int tend = min(t0 + CHUNK, ctx);
  const int ntok = tend - t0;
  const int pos  = ctx - 1;
  const bool has_new = (pos >= t0) && (pos < tend);
  const int ncache = has_new ? (pos - t0) : ntok;

  const int tid  = threadIdx.x;
  const int lane = tid & 63;
  const int w    = tid >> 6;
  const int sub  = lane >> 4;
  const int li   = lane & 15;

  __shared__ float cs_lds[64];
  __shared__ float sn_lds[64];
  __shared__ float qrot[GRP * HD];       // 2 KB
  __shared__ float krot[HD];             // 512 B
  __shared__ int   bt[CHUNK / BS];       // 16 entries
  __shared__ float snew_lds[GRP];
  __shared__ float m_lds[4][GRP];
  __shared__ float l_lds[4][GRP];
  __shared__ float acc_lds[4][GRP][HD];  // 8 KB

  if (tid < 64) {
    cs_lds[tid] = cos_cache[pos * 64 + tid];
    sn_lds[tid] = sin_cache[pos * 64 + tid];
  }
  if (tid >= 192 && tid < 192 + CHUNK / BS)
    bt[tid - 192] = block_tables[s * BPS + (t0 >> 4) + (tid - 192)];
  __syncthreads();

  // RoPE q (SCALE folded in) into LDS
  {
    const float* qp = q + (s * NH + kv * GRP) * HD;
#pragma unroll
    for (int j = tid; j < GRP * HD; j += 256) {
      int h = j >> 7, d = j & 127;
      float r;
      if (d < 64) r = qp[h * HD + d] * cs_lds[d] - qp[h * HD + d + 64] * sn_lds[d];
      else        r = qp[h * HD + d] * cs_lds[d - 64] + qp[h * HD + d - 64] * sn_lds[d - 64];
      qrot[j] = r * SCALE;
    }
  }
  if (has_new && tid < 128) {
    const float* kp = k_new + (s * NKV + kv) * HD;
    int d = tid;
    float r;
    if (d < 64) r = kp[d] * cs_lds[d] - kp[d + 64] * sn_lds[d];
    else        r = kp[d] * cs_lds[d - 64] + kp[d - 64] * sn_lds[d - 64];
    krot[d] = r;
  }
  __syncthreads();

  float4 qf0[GRP], qf1[GRP];
#pragma unroll
  for (int h = 0; h < GRP; ++h) {
    qf0[h] = *(const float4*)&qrot[h * HD + li * 4];
    qf1[h] = *(const float4*)&qrot[h * HD + 64 + li * 4];
  }

  // new-token scores (wave 0) -> snew_lds
  if (w == 0 && has_new) {
    float4 ka = *(const float4*)&krot[li * 4];
    float4 kb = *(const float4*)&krot[64 + li * 4];
    float p0 = red16(dot8(qf0[0], qf1[0], ka, kb));
    float p1 = red16(dot8(qf0[1], qf1[1], ka, kb));
    float p2 = red16(dot8(qf0[2], qf1[2], ka, kb));
    float p3 = red16(dot8(qf0[3], qf1[3], ka, kb));
    if (lane == 0) {
      snew_lds[0] = p0; snew_lds[1] = p1;
      snew_lds[2] = p2; snew_lds[3] = p3;
    }
  }

  // ---- fused K+V single pass, online softmax ----
  float m0 = NEGINF, m1 = NEGINF, m2 = NEGINF, m3 = NEGINF;
  float l0 = 0.f, l1 = 0.f, l2 = 0.f, l3 = 0.f;
  float4 aa0 = {0,0,0,0}, aa1 = {0,0,0,0}, aa2 = {0,0,0,0}, aa3 = {0,0,0,0};
  float4 ab0 = {0,0,0,0}, ab1 = {0,0,0,0}, ab2 = {0,0,0,0}, ab3 = {0,0,0,0};

  for (int j0 = w * 4; j0 < ncache; j0 += 16) {
    int j = j0 + sub;
    bool valid = j < ncache;
    int jc = valid ? j : (ncache - 1);
    int blk = bt[jc >> 4];
    int a = ((blk * BS + (jc & 15)) * NKV + kv) * HD + li * 4;
    float4 ka = *(const float4*)&k_cache[a];
    float4 kb = *(const float4*)&k_cache[a + 64];
    float4 va = *(const float4*)&v_cache[a];
    float4 vb = *(const float4*)&v_cache[a + 64];

    float s0 = red16(dot8(qf0[0], qf1[0], ka, kb));
    float s1 = red16(dot8(qf0[1], qf1[1], ka, kb));
    float s2 = red16(dot8(qf0[2], qf1[2], ka, kb));
    float s3 = red16(dot8(qf0[3], qf1[3], ka, kb));
    if (!valid) { s0 = NEGINF; s1 = NEGINF; s2 = NEGINF; s3 = NEGINF; }

    // wave max over the 4 token-subgroups
    float n0 = fmaxf(s0, __shfl_xor(s0, 16)); n0 = fmaxf(n0, __shfl_xor(n0, 32));
    float n1 = fmaxf(s1, __shfl_xor(s1, 16)); n1 = fmaxf(n1, __shfl_xor(n1, 32));
    float n2 = fmaxf(s2, __shfl_xor(s2, 16)); n2 = fmaxf(n2, __shfl_xor(n2, 32));
    float n3 = fmaxf(s3, __shfl_xor(s3, 16)); n3 = fmaxf(n3, __shfl_xor(n3, 32));

    if (n0 > m0 || n1 > m1 || n2 > m2 || n3 > m3) {   // wave-uniform
      float t0_ = fmaxf(m0, n0), f0 = __expf(m0 - t0_); m0 = t0_;
      float t1_ = fmaxf(m1, n1), f1 = __expf(m1 - t1_); m1 = t1_;
      float t2_ = fmaxf(m2, n2), f2 = __expf(m2 - t2_); m2 = t2_;
      float t3_ = fmaxf(m3, n3), f3 = __expf(m3 - t3_); m3 = t3_;
      l0 *= f0; l1 *= f1; l2 *= f2; l3 *= f3;
      aa0.x *= f0; aa0.y *= f0; aa0.z *= f0; aa0.w *= f0;
      ab0.x *= f0; ab0.y *= f0; ab0.z *= f0; ab0.w *= f0;
      aa1.x *= f1; aa1.y *= f1; aa1.z *= f1; aa1.w *= f1;
      ab1.x *= f1; ab1.y *= f1; ab1.z *= f1; ab1.w *= f1;
      aa2.x *= f2; aa2.y *= f2; aa2.z *= f2; aa2.w *= f2;
      ab2.x *= f2; ab2.y *= f2; ab2.z *= f2; ab2.w *= f2;
      aa3.x *= f3; aa3.y *= f3; aa3.z *= f3; aa3.w *= f3;
      ab3.x *= f3; ab3.y *= f3; ab3.z *= f3; ab3.w *= f3;
    }

    float p0 = __expf(s0 - m0);
    float p1 = __expf(s1 - m1);
    float p2 = __expf(s2 - m2);
    float p3 = __expf(s3 - m3);
    l0 += p0; l1 += p1; l2 += p2; l3 += p3;

    aa0.x = fmaf(p0, va.x, aa0.x); aa0.y = fmaf(p0, va.y, aa0.y);
    aa0.z = fmaf(p0, va.z, aa0.z); aa0.w = fmaf(p0, va.w, aa0.w);
    ab0.x = fmaf(p0, vb.x, ab0.x); ab0.y = fmaf(p0, vb.y, ab0.y);
    ab0.z = fmaf(p0, vb.z, ab0.z); ab0.w = fmaf(p0, vb.w, ab0.w);
    aa1.x = fmaf(p1, va.x, aa1.x); aa1.y = fmaf(p1, va.y, aa1.y);
    aa1.z = fmaf(p1, va.z, aa1.z); aa1.w = fmaf(p1, va.w, aa1.w);
    ab1.x = fmaf(p1, vb.x, ab1.x); ab1.y = fmaf(p1, vb.y, ab1.y);
    ab1.z = fmaf(p1, vb.z, ab1.z); ab1.w = fmaf(p1, vb.w, ab1.w);
    aa2.x = fmaf(p2, va.x, aa2.x); aa2.y = fmaf(p2, va.y, aa2.y);
    aa2.z = fmaf(p2, va.z, aa2.z); aa2.w = fmaf(p2, va.w, aa2.w);
    ab2.x = fmaf(p2, vb.x, ab2.x); ab2.y = fmaf(p2, vb.y, ab2.y);
    ab2.z = fmaf(p2, vb.z, ab2.z); ab2.w = fmaf(p2, vb.w, ab2.w);
    aa3.x = fmaf(p3, va.x, aa3.x); aa3.y = fmaf(p3, va.y, aa3.y);
    aa3.z = fmaf(p3, va.z, aa3.z); aa3.w = fmaf(p3, va.w, aa3.w);
    ab3.x = fmaf(p3, vb.x, ab3.x); ab3.y = fmaf(p3, vb.y, ab3.y);
    ab3.z = fmaf(p3, vb.z, ab3.z); ab3.w = fmaf(p3, vb.w, ab3.w);
  }

  // combine the 4 token-subgroups (same m scale within the wave)
  red_sub(aa0); red_sub(aa1); red_sub(aa2); red_sub(aa3);
  red_sub(ab0); red_sub(ab1); red_sub(ab2); red_sub(ab3);
  l0 += __shfl_xor(l0, 16); l0 += __shfl_xor(l0, 32);
  l1 += __shfl_xor(l1, 16); l1 += __shfl_xor(l1, 32);
  l2 += __shfl_xor(l2, 16); l2 += __shfl_xor(l2, 32);
  l3 += __shfl_xor(l3, 16); l3 += __shfl_xor(l3, 32);

  if (lane < 16) {
    *(float4*)&acc_lds[w][0][li * 4] = aa0;
    *(float4*)&acc_lds[w][1][li * 4] = aa1;
    *(float4*)&acc_lds[w][2][li * 4] = aa2;
    *(float4*)&acc_lds[w][3][li * 4] = aa3;
    *(float4*)&acc_lds[w][0][64 + li * 4] = ab0;
    *(float4*)&acc_lds[w][1][64 + li * 4] = ab1;
    *(float4*)&acc_lds[w][2][64 + li * 4] = ab2;
    *(float4*)&acc_lds[w][3][64 + li * 4] = ab3;
  }
  if (lane == 0) {
    m_lds[w][0] = m0; m_lds[w][1] = m1; m_lds[w][2] = m2; m_lds[w][3] = m3;
    l_lds[w][0] = l0; l_lds[w][1] = l1; l_lds[w][2] = l2; l_lds[w][3] = l3;
  }
  __syncthreads();

  // ---- epilogue: LSE-merge waves (+ new token), write UNNORMALIZED partial ----
  {
    const float* vp = v_new + (s * NKV + kv) * HD;
#pragma unroll
    for (int jj = tid; jj < GRP * HD; jj += 256) {
      int h = jj >> 7, d = jj & 127;
      float mw0 = m_lds[0][h], mw1 = m_lds[1][h], mw2 = m_lds[2][h], mw3 = m_lds[3][h];
      float ms = fmaxf(fmaxf(mw0, mw1), fmaxf(mw2, mw3));
      if (has_new) ms = fmaxf(ms, snew_lds[h]);
      float o = __expf(mw0 - ms) * acc_lds[0][h][d]
              + __expf(mw1 - ms) * acc_lds[1][h][d]
              + __expf(mw2 - ms) * acc_lds[2][h][d]
              + __expf(mw3 - ms) * acc_lds[3][h][d];
      if (has_new) o = fmaf(__expf(snew_lds[h] - ms), vp[d], o);
      int part = ((s * NKV + kv) * GRP + h) * NSPLIT + sp;
      accW[part * HD + d] = o;
    }
    if (tid < GRP) {
      int h = tid;
      float mw0 = m_lds[0][h], mw1 = m_lds[1][h], mw2 = m_lds[2][h], mw3 = m_lds[3][h];
      float ms = fmaxf(fmaxf(mw0, mw1), fmaxf(mw2, mw3));
      if (has_new) ms = fmaxf(ms, snew_lds[h]);
      float L = __expf(mw0 - ms) * l_lds[0][h]
              + __expf(mw1 - ms) * l_lds[1][h]
              + __expf(mw2 - ms) * l_lds[2][h]
              + __expf(mw3 - ms) * l_lds[3][h];
      if (has_new) L += __expf(snew_lds[h] - ms);
      mlW[((s * NKV + kv) * GRP + h) * NSPLIT + sp] = make_float2(ms, L);
    }
  }
}

// LSE-combine the per-split partials. One wave per (seq, head).
extern "C" __global__ __launch_bounds__(256, 8)
void paged_reduce(const float* __restrict__ accW,
                  const float2* __restrict__ mlW,
                  const int* __restrict__ context_lens,
                  float* __restrict__ out)
{
  const int tid  = threadIdx.x;
  const int lane = tid & 63;
  const int w    = tid >> 6;
  const int idx  = blockIdx.x * 4 + w;   // 0..1023 = (s, h)
  const int s    = idx >> 5;
  const int h    = idx & 31;
  const int kv   = h >> 2, g = h & 3;
  const int ctx  = context_lens[s];
  const int nsp  = (ctx + CHUNK - 1) / CHUNK;
  const int pbase = ((s * NKV + kv) * GRP + g) * NSPLIT;

  float m = NEGINF;
  for (int i = 0; i < nsp; ++i) m = fmaxf(m, mlW[pbase + i].x);
  float L = 0.f;
  float2 acc = {0.f, 0.f};
  for (int i = 0; i < nsp; ++i) {
    float2 ml = mlW[pbase + i];
    float sc = __expf(ml.x - m);
    L += ml.y * sc;
    float2 a = *(const float2*)&accW[(pbase + i) * HD + lane * 2];
    acc.x = fmaf(a.x, sc, acc.x);
    acc.y = fmaf(a.y, sc, acc.y);
  }
  float inv = 1.0f / L;
  float2 o = make_float2(acc.x * inv, acc.y * inv);
  *(float2*)&out[(s * NH + h) * HD + lane * 2] = o;
}

extern "C" void kernel_launch(void* const* d_in, const int* in_sizes, int n_in,
                              void* d_out, int out_size, void* d_ws, size_t ws_size,
                              hipStream_t stream) {
  const float* q         = (const float*)d_in[0];
  const float* k_new     = (const float*)d_in[1];
  const float* v_new     = (const float*)d_in[2];
  const float* k_cache   = (const float*)d_in[3];
  const float* v_cache   = (const float*)d_in[4];
  const float* cos_cache = (const float*)d_in[5];
  const float* sin_cache = (const float*)d_in[6];
  const int* block_tables = (const int*)d_in[9];
  const int* context_lens = (const int*)d_in[10];
  float* out = (float*)d_out;

  float*  accW = (float*)d_ws;   // NSEQ*NKV*GRP*NSPLIT*HD floats = 4 MB
  float2* mlW  = (float2*)((char*)d_ws + (size_t)NSEQ * NKV * GRP * NSPLIT * HD * sizeof(float));

  dim3 grid(NKV, NSEQ * NSPLIT);   // y = dense active-split index
  paged_split<<<grid, 256, 0, stream>>>(q, k_new, v_new, k_cache, v_cache,
                                        cos_cache, sin_cache, block_tables,
                                        context_lens, accW, mlW);
  paged_reduce<<<NSEQ * NH / 4, 256, 0, stream>>>(accW, mlW, context_lens, out);
}

// Round 10
// 59.432 us; speedup vs baseline: 1.1507x; 1.1507x over previous
//
#include <hip/hip_runtime.h>

#define NSEQ 32
#define NH 32
#define NKV 8
#define GRP 4
#define HD 128
#define BS 16
#define MAXCTX 2048
#define BPS 128
#define CHUNK 256
#define NSPLIT (MAXCTX / CHUNK)   // 8
#define SCALE 0.08838834764831845f

__device__ __forceinline__ float dot8(float4 qa, float4 qb, float4 ka, float4 kb) {
  float r = qa.x * ka.x;
  r = fmaf(qa.y, ka.y, r);
  r = fmaf(qa.z, ka.z, r);
  r = fmaf(qa.w, ka.w, r);
  r = fmaf(qb.x, kb.x, r);
  r = fmaf(qb.y, kb.y, r);
  r = fmaf(qb.z, kb.z, r);
  r = fmaf(qb.w, kb.w, r);
  return r;
}

// 16-lane sum entirely on the VALU pipe (DPP), no LDS/shfl traffic:
// xor1 = quad_perm[1,0,3,2] (0xB1), xor2 = quad_perm[2,3,0,1] (0x4E),
// then row_half_mirror (0x141) pairs i<->7-i (other quad, quad-sums equal),
// then row_mirror (0x140) pairs i<->15-i (other 8-group). All 16 lanes end
// with the full 16-lane sum.
__device__ __forceinline__ float red16_dpp(float x) {
  x += __int_as_float(__builtin_amdgcn_update_dpp(0, __float_as_int(x), 0xB1, 0xF, 0xF, true));
  x += __int_as_float(__builtin_amdgcn_update_dpp(0, __float_as_int(x), 0x4E, 0xF, 0xF, true));
  x += __int_as_float(__builtin_amdgcn_update_dpp(0, __float_as_int(x), 0x141, 0xF, 0xF, true));
  x += __int_as_float(__builtin_amdgcn_update_dpp(0, __float_as_int(x), 0x140, 0xF, 0xF, true));
  return x;
}

__device__ __forceinline__ void red_sub(float4& v) {
  v.x += __shfl_xor(v.x, 16); v.y += __shfl_xor(v.y, 16);
  v.z += __shfl_xor(v.z, 16); v.w += __shfl_xor(v.w, 16);
  v.x += __shfl_xor(v.x, 32); v.y += __shfl_xor(v.y, 32);
  v.z += __shfl_xor(v.z, 32); v.w += __shfl_xor(v.w, 32);
}

// One workgroup per (kv-head, dense-active-split). Block scans context_lens to
// map its dense index -> (seq, split); inactive tail blocks exit immediately.
// Produces an UNNORMALIZED partial (m, l, acc[GRP][HD]) per 256-token chunk.
extern "C" __global__ __launch_bounds__(256, 8)
void paged_split(const float* __restrict__ q,
                 const float* __restrict__ k_new,
                 const float* __restrict__ v_new,
                 const float* __restrict__ k_cache,
                 const float* __restrict__ v_cache,
                 const float* __restrict__ cos_cache,
                 const float* __restrict__ sin_cache,
                 const int* __restrict__ block_tables,
                 const int* __restrict__ context_lens,
                 float* __restrict__ accW,
                 float2* __restrict__ mlW)
{
  const int kv = blockIdx.x;   // 0..7
  // ---- dense remap: blockIdx.y -> (s, sp), wave-uniform scan ----
  int s = -1, sp = blockIdx.y;
  for (int i = 0; i < NSEQ; ++i) {
    int ns = (context_lens[i] + CHUNK - 1) / CHUNK;
    if (sp < ns) { s = i; break; }
    sp -= ns;
  }
  if (s < 0) return;

  const int ctx = context_lens[s];
  const int t0  = sp * CHUNK;
  const int tend = min(t0 + CHUNK, ctx);
  const int ntok = tend - t0;
  const int pos  = ctx - 1;
  const bool has_new = (pos >= t0) && (pos < tend);
  const int ncache = has_new ? (pos - t0) : ntok;

  const int tid  = threadIdx.x;
  const int lane = tid & 63;
  const int w    = tid >> 6;
  const int sub  = lane >> 4;
  const int li   = lane & 15;

  __shared__ float cs_lds[64];
  __shared__ float sn_lds[64];
  __shared__ float qrot[GRP * HD];       // 2 KB
  __shared__ float krot[HD];             // 512 B
  __shared__ int   bt[CHUNK / BS];       // 16 entries
  __shared__ float s_sc[GRP][CHUNK];     // 4 KB (scores -> p)
  __shared__ float acc_lds[4][GRP][HD];  // 8 KB

  if (tid < 64) {
    cs_lds[tid] = cos_cache[pos * 64 + tid];
    sn_lds[tid] = sin_cache[pos * 64 + tid];
  }
  if (tid >= 192 && tid < 192 + CHUNK / BS)
    bt[tid - 192] = block_tables[s * BPS + (t0 >> 4) + (tid - 192)];
  __syncthreads();

  // RoPE q (SCALE folded in) into LDS
  {
    const float* qp = q + (s * NH + kv * GRP) * HD;
#pragma unroll
    for (int j = tid; j < GRP * HD; j += 256) {
      int h = j >> 7, d = j & 127;
      float r;
      if (d < 64) r = qp[h * HD + d] * cs_lds[d] - qp[h * HD + d + 64] * sn_lds[d];
      else        r = qp[h * HD + d] * cs_lds[d - 64] + qp[h * HD + d - 64] * sn_lds[d - 64];
      qrot[j] = r * SCALE;
    }
  }
  if (has_new && tid < 128) {
    const float* kp = k_new + (s * NKV + kv) * HD;
    int d = tid;
    float r;
    if (d < 64) r = kp[d] * cs_lds[d] - kp[d + 64] * sn_lds[d];
    else        r = kp[d] * cs_lds[d - 64] + kp[d - 64] * sn_lds[d - 64];
    krot[d] = r;
  }
  __syncthreads();

  float4 qf0[GRP], qf1[GRP];
#pragma unroll
  for (int h = 0; h < GRP; ++h) {
    qf0[h] = *(const float4*)&qrot[h * HD + li * 4];
    qf1[h] = *(const float4*)&qrot[h * HD + 64 + li * 4];
  }

  // new-token score (local index == ncache), wave 0
  if (w == 0 && has_new) {
    float4 ka = *(const float4*)&krot[li * 4];
    float4 kb = *(const float4*)&krot[64 + li * 4];
    float p0 = red16_dpp(dot8(qf0[0], qf1[0], ka, kb));
    float p1 = red16_dpp(dot8(qf0[1], qf1[1], ka, kb));
    float p2 = red16_dpp(dot8(qf0[2], qf1[2], ka, kb));
    float p3 = red16_dpp(dot8(qf0[3], qf1[3], ka, kb));
    if (lane == 0) {
      s_sc[0][ncache] = p0; s_sc[1][ncache] = p1;
      s_sc[2][ncache] = p2; s_sc[3][ncache] = p3;
    }
  }

  // pass 1: QK^T over local cache tokens [0, ncache).
  // All cross-lane reduction on the VALU pipe (DPP); lanes 0-3 of each
  // 16-lane token-group write the 4 head scores.
  for (int j0 = w * 4; j0 < ncache; j0 += 16) {
    int j = j0 + sub;
    int jc = j < ncache ? j : (ncache - 1);
    int blk = bt[jc >> 4];
    int a = ((blk * BS + (jc & 15)) * NKV + kv) * HD + li * 4;
    float4 ka = *(const float4*)&k_cache[a];
    float4 kb = *(const float4*)&k_cache[a + 64];
    float p0 = red16_dpp(dot8(qf0[0], qf1[0], ka, kb));
    float p1 = red16_dpp(dot8(qf0[1], qf1[1], ka, kb));
    float p2 = red16_dpp(dot8(qf0[2], qf1[2], ka, kb));
    float p3 = red16_dpp(dot8(qf0[3], qf1[3], ka, kb));
    if (li < 4 && j < ncache) {
      float x = (li == 0) ? p0 : (li == 1) ? p1 : (li == 2) ? p2 : p3;
      s_sc[li][j] = x;
    }
  }
  __syncthreads();

  // softmax partial: wave w handles head w over [0, ntok)
  {
    float m = -3.0e38f;
    for (int t = lane; t < ntok; t += 64) m = fmaxf(m, s_sc[w][t]);
#pragma unroll
    for (int msk = 1; msk < 64; msk <<= 1) m = fmaxf(m, __shfl_xor(m, msk));
    float sum = 0.f;
    for (int t = lane; t < ntok; t += 64) {
      float p = __expf(s_sc[w][t] - m);
      s_sc[w][t] = p;
      sum += p;
    }
#pragma unroll
    for (int msk = 1; msk < 64; msk <<= 1) sum += __shfl_xor(sum, msk);
    if (lane == 0) {
      int part = ((s * NKV + kv) * GRP + w) * NSPLIT + sp;
      mlW[part] = make_float2(m, sum);
    }
  }
  __syncthreads();

  // pass 2: P·V over local cache tokens
  float4 aa0 = {0,0,0,0}, aa1 = {0,0,0,0}, aa2 = {0,0,0,0}, aa3 = {0,0,0,0};
  float4 ab0 = {0,0,0,0}, ab1 = {0,0,0,0}, ab2 = {0,0,0,0}, ab3 = {0,0,0,0};
  for (int j0 = w * 4; j0 < ncache; j0 += 16) {
    int j = j0 + sub;
    int jc = j < ncache ? j : (ncache - 1);
    int blk = bt[jc >> 4];
    int a = ((blk * BS + (jc & 15)) * NKV + kv) * HD + li * 4;
    float4 va = *(const float4*)&v_cache[a];
    float4 vb = *(const float4*)&v_cache[a + 64];
    bool valid = j < ncache;
    float p0 = valid ? s_sc[0][j] : 0.f;
    float p1 = valid ? s_sc[1][j] : 0.f;
    float p2 = valid ? s_sc[2][j] : 0.f;
    float p3 = valid ? s_sc[3][j] : 0.f;
    aa0.x = fmaf(p0, va.x, aa0.x); aa0.y = fmaf(p0, va.y, aa0.y);
    aa0.z = fmaf(p0, va.z, aa0.z); aa0.w = fmaf(p0, va.w, aa0.w);
    ab0.x = fmaf(p0, vb.x, ab0.x); ab0.y = fmaf(p0, vb.y, ab0.y);
    ab0.z = fmaf(p0, vb.z, ab0.z); ab0.w = fmaf(p0, vb.w, ab0.w);
    aa1.x = fmaf(p1, va.x, aa1.x); aa1.y = fmaf(p1, va.y, aa1.y);
    aa1.z = fmaf(p1, va.z, aa1.z); aa1.w = fmaf(p1, va.w, aa1.w);
    ab1.x = fmaf(p1, vb.x, ab1.x); ab1.y = fmaf(p1, vb.y, ab1.y);
    ab1.z = fmaf(p1, vb.z, ab1.z); ab1.w = fmaf(p1, vb.w, ab1.w);
    aa2.x = fmaf(p2, va.x, aa2.x); aa2.y = fmaf(p2, va.y, aa2.y);
    aa2.z = fmaf(p2, va.z, aa2.z); aa2.w = fmaf(p2, va.w, aa2.w);
    ab2.x = fmaf(p2, vb.x, ab2.x); ab2.y = fmaf(p2, vb.y, ab2.y);
    ab2.z = fmaf(p2, vb.z, ab2.z); ab2.w = fmaf(p2, vb.w, ab2.w);
    aa3.x = fmaf(p3, va.x, aa3.x); aa3.y = fmaf(p3, va.y, aa3.y);
    aa3.z = fmaf(p3, va.z, aa3.z); aa3.w = fmaf(p3, va.w, aa3.w);
    ab3.x = fmaf(p3, vb.x, ab3.x); ab3.y = fmaf(p3, vb.y, ab3.y);
    ab3.z = fmaf(p3, vb.z, ab3.z); ab3.w = fmaf(p3, vb.w, ab3.w);
  }
  red_sub(aa0); red_sub(aa1); red_sub(aa2); red_sub(aa3);
  red_sub(ab0); red_sub(ab1); red_sub(ab2); red_sub(ab3);
  if (lane < 16) {
    *(float4*)&acc_lds[w][0][li * 4] = aa0;
    *(float4*)&acc_lds[w][1][li * 4] = aa1;
    *(float4*)&acc_lds[w][2][li * 4] = aa2;
    *(float4*)&acc_lds[w][3][li * 4] = aa3;
    *(float4*)&acc_lds[w][0][64 + li * 4] = ab0;
    *(float4*)&acc_lds[w][1][64 + li * 4] = ab1;
    *(float4*)&acc_lds[w][2][64 + li * 4] = ab2;
    *(float4*)&acc_lds[w][3][64 + li * 4] = ab3;
  }
  __syncthreads();

  // epilogue: combine waves, add new-token V, write UNNORMALIZED partial
  {
    const float* vp = v_new + (s * NKV + kv) * HD;
#pragma unroll
    for (int j = tid; j < GRP * HD; j += 256) {
      int h = j >> 7, d = j & 127;
      float o = acc_lds[0][h][d] + acc_lds[1][h][d] + acc_lds[2][h][d] + acc_lds[3][h][d];
      if (has_new) o = fmaf(s_sc[h][ncache], vp[d], o);
      int part = ((s * NKV + kv) * GRP + h) * NSPLIT + sp;
      accW[part * HD + d] = o;
    }
  }
}

// LSE-combine the per-split partials. One wave per (seq, head).
extern "C" __global__ __launch_bounds__(256, 8)
void paged_reduce(const float* __restrict__ accW,
                  const float2* __restrict__ mlW,
                  const int* __restrict__ context_lens,
                  float* __restrict__ out)
{
  const int tid  = threadIdx.x;
  const int lane = tid & 63;
  const int w    = tid >> 6;
  const int idx  = blockIdx.x * 4 + w;   // 0..1023 = (s, h)
  const int s    = idx >> 5;
  const int h    = idx & 31;
  const int kv   = h >> 2, g = h & 3;
  const int ctx  = context_lens[s];
  const int nsp  = (ctx + CHUNK - 1) / CHUNK;
  const int pbase = ((s * NKV + kv) * GRP + g) * NSPLIT;

  float m = -3.0e38f;
  for (int i = 0; i < nsp; ++i) m = fmaxf(m, mlW[pbase + i].x);
  float L = 0.f;
  float2 acc = {0.f, 0.f};
  for (int i = 0; i < nsp; ++i) {
    float2 ml = mlW[pbase + i];
    float sc = __expf(ml.x - m);
    L += ml.y * sc;
    float2 a = *(const float2*)&accW[(pbase + i) * HD + lane * 2];
    acc.x = fmaf(a.x, sc, acc.x);
    acc.y = fmaf(a.y, sc, acc.y);
  }
  float inv = 1.0f / L;
  float2 o = make_float2(acc.x * inv, acc.y * inv);
  *(float2*)&out[(s * NH + h) * HD + lane * 2] = o;
}

extern "C" void kernel_launch(void* const* d_in, const int* in_sizes, int n_in,
                              void* d_out, int out_size, void* d_ws, size_t ws_size,
                              hipStream_t stream) {
  const float* q         = (const float*)d_in[0];
  const float* k_new     = (const float*)d_in[1];
  const float* v_new     = (const float*)d_in[2];
  const float* k_cache   = (const float*)d_in[3];
  const float* v_cache   = (const float*)d_in[4];
  const float* cos_cache = (const float*)d_in[5];
  const float* sin_cache = (const float*)d_in[6];
  const int* block_tables = (const int*)d_in[9];
  const int* context_lens = (const int*)d_in[10];
  float* out = (float*)d_out;

  float*  accW = (float*)d_ws;   // NSEQ*NKV*GRP*NSPLIT*HD floats = 4 MB
  float2* mlW  = (float2*)((char*)d_ws + (size_t)NSEQ * NKV * GRP * NSPLIT * HD * sizeof(float));

  dim3 grid(NKV, NSEQ * NSPLIT);   // y = dense active-split index
  paged_split<<<grid, 256, 0, stream>>>(q, k_new, v_new, k_cache, v_cache,
                                        cos_cache, sin_cache, block_tables,
                                        context_lens, accW, mlW);
  paged_reduce<<<NSEQ * NH / 4, 256, 0, stream>>>(accW, mlW, context_lens, out);
}

// Round 11
// 57.685 us; speedup vs baseline: 1.1856x; 1.0303x over previous
//
#include <hip/hip_runtime.h>

#define NSEQ 32
#define NH 32
#define NKV 8
#define GRP 4
#define HD 128
#define BS 16
#define MAXCTX 2048
#define BPS 128
#define CHUNK 256
#define NSPLIT (MAXCTX / CHUNK)   // 8
#define SCALE 0.08838834764831845f

__device__ __forceinline__ float dot8(float4 qa, float4 qb, float4 ka, float4 kb) {
  float r = qa.x * ka.x;
  r = fmaf(qa.y, ka.y, r);
  r = fmaf(qa.z, ka.z, r);
  r = fmaf(qa.w, ka.w, r);
  r = fmaf(qb.x, kb.x, r);
  r = fmaf(qb.y, kb.y, r);
  r = fmaf(qb.z, kb.z, r);
  r = fmaf(qb.w, kb.w, r);
  return r;
}

// 16-lane sum entirely on the VALU pipe (DPP).
__device__ __forceinline__ float red16_dpp(float x) {
  x += __int_as_float(__builtin_amdgcn_update_dpp(0, __float_as_int(x), 0xB1, 0xF, 0xF, true));
  x += __int_as_float(__builtin_amdgcn_update_dpp(0, __float_as_int(x), 0x4E, 0xF, 0xF, true));
  x += __int_as_float(__builtin_amdgcn_update_dpp(0, __float_as_int(x), 0x141, 0xF, 0xF, true));
  x += __int_as_float(__builtin_amdgcn_update_dpp(0, __float_as_int(x), 0x140, 0xF, 0xF, true));
  return x;
}

__device__ __forceinline__ void red_sub(float4& v) {
  v.x += __shfl_xor(v.x, 16); v.y += __shfl_xor(v.y, 16);
  v.z += __shfl_xor(v.z, 16); v.w += __shfl_xor(v.w, 16);
  v.x += __shfl_xor(v.x, 32); v.y += __shfl_xor(v.y, 32);
  v.z += __shfl_xor(v.z, 32); v.w += __shfl_xor(v.w, 32);
}

// One workgroup per (kv-head, dense-active-split).
// Batch-4 load pipelining: each wave issues 8 float4 loads (4 token-groups)
// back-to-back before computing, both passes. 4 blocks/CU (<=128 VGPR).
extern "C" __global__ __launch_bounds__(256, 4)
void paged_split(const float* __restrict__ q,
                 const float* __restrict__ k_new,
                 const float* __restrict__ v_new,
                 const float* __restrict__ k_cache,
                 const float* __restrict__ v_cache,
                 const float* __restrict__ cos_cache,
                 const float* __restrict__ sin_cache,
                 const int* __restrict__ block_tables,
                 const int* __restrict__ context_lens,
                 float* __restrict__ accW,
                 float2* __restrict__ mlW)
{
  const int kv = blockIdx.x;   // 0..7
  // ---- dense remap: blockIdx.y -> (s, sp), wave-uniform scan ----
  int s = -1, sp = blockIdx.y;
  for (int i = 0; i < NSEQ; ++i) {
    int ns = (context_lens[i] + CHUNK - 1) / CHUNK;
    if (sp < ns) { s = i; break; }
    sp -= ns;
  }
  if (s < 0) return;

  const int ctx = context_lens[s];
  const int t0  = sp * CHUNK;
  const int tend = min(t0 + CHUNK, ctx);
  const int ntok = tend - t0;
  const int pos  = ctx - 1;
  const bool has_new = (pos >= t0) && (pos < tend);
  const int ncache = has_new ? (pos - t0) : ntok;

  const int tid  = threadIdx.x;
  const int lane = tid & 63;
  const int w    = tid >> 6;
  const int sub  = lane >> 4;
  const int li   = lane & 15;

  __shared__ float cs_lds[64];
  __shared__ float sn_lds[64];
  __shared__ float qrot[GRP * HD];       // 2 KB
  __shared__ float krot[HD];             // 512 B
  __shared__ int   bt[CHUNK / BS];       // 16 entries
  __shared__ float s_sc[GRP][CHUNK];     // 4 KB (scores -> p)
  __shared__ float acc_lds[4][GRP][HD];  // 8 KB

  if (tid < 64) {
    cs_lds[tid] = cos_cache[pos * 64 + tid];
    sn_lds[tid] = sin_cache[pos * 64 + tid];
  }
  if (tid >= 192 && tid < 192 + CHUNK / BS)
    bt[tid - 192] = block_tables[s * BPS + (t0 >> 4) + (tid - 192)];
  __syncthreads();

  // RoPE q (SCALE folded in) into LDS
  {
    const float* qp = q + (s * NH + kv * GRP) * HD;
#pragma unroll
    for (int j = tid; j < GRP * HD; j += 256) {
      int h = j >> 7, d = j & 127;
      float r;
      if (d < 64) r = qp[h * HD + d] * cs_lds[d] - qp[h * HD + d + 64] * sn_lds[d];
      else        r = qp[h * HD + d] * cs_lds[d - 64] + qp[h * HD + d - 64] * sn_lds[d - 64];
      qrot[j] = r * SCALE;
    }
  }
  if (has_new && tid < 128) {
    const float* kp = k_new + (s * NKV + kv) * HD;
    int d = tid;
    float r;
    if (d < 64) r = kp[d] * cs_lds[d] - kp[d + 64] * sn_lds[d];
    else        r = kp[d] * cs_lds[d - 64] + kp[d - 64] * sn_lds[d - 64];
    krot[d] = r;
  }
  __syncthreads();

  float4 qf0[GRP], qf1[GRP];
#pragma unroll
  for (int h = 0; h < GRP; ++h) {
    qf0[h] = *(const float4*)&qrot[h * HD + li * 4];
    qf1[h] = *(const float4*)&qrot[h * HD + 64 + li * 4];
  }

  // new-token score (local index == ncache), wave 0
  if (w == 0 && has_new) {
    float4 ka = *(const float4*)&krot[li * 4];
    float4 kb = *(const float4*)&krot[64 + li * 4];
    float p0 = red16_dpp(dot8(qf0[0], qf1[0], ka, kb));
    float p1 = red16_dpp(dot8(qf0[1], qf1[1], ka, kb));
    float p2 = red16_dpp(dot8(qf0[2], qf1[2], ka, kb));
    float p3 = red16_dpp(dot8(qf0[3], qf1[3], ka, kb));
    if (lane == 0) {
      s_sc[0][ncache] = p0; s_sc[1][ncache] = p1;
      s_sc[2][ncache] = p2; s_sc[3][ncache] = p3;
    }
  }

  // addresses for 4 token-groups starting at j0 (this lane handles j0+sub+16u)
#define ADDR4(j0)                                                        \
  int j_0 = (j0) + sub,      j_1 = j_0 + 16, j_2 = j_0 + 32, j_3 = j_0 + 48; \
  int jc0 = j_0 < ncache ? j_0 : ncache - 1;                             \
  int jc1 = j_1 < ncache ? j_1 : ncache - 1;                             \
  int jc2 = j_2 < ncache ? j_2 : ncache - 1;                             \
  int jc3 = j_3 < ncache ? j_3 : ncache - 1;                             \
  int a0 = ((bt[jc0 >> 4] * BS + (jc0 & 15)) * NKV + kv) * HD + li * 4;  \
  int a1 = ((bt[jc1 >> 4] * BS + (jc1 & 15)) * NKV + kv) * HD + li * 4;  \
  int a2 = ((bt[jc2 >> 4] * BS + (jc2 & 15)) * NKV + kv) * HD + li * 4;  \
  int a3 = ((bt[jc3 >> 4] * BS + (jc3 & 15)) * NKV + kv) * HD + li * 4;

  // pass 1: QK^T, batch-4 loads then compute
  for (int j0 = w * 4; j0 < ncache; j0 += 64) {
    ADDR4(j0)
    float4 k0a = *(const float4*)&k_cache[a0];
    float4 k0b = *(const float4*)&k_cache[a0 + 64];
    float4 k1a = *(const float4*)&k_cache[a1];
    float4 k1b = *(const float4*)&k_cache[a1 + 64];
    float4 k2a = *(const float4*)&k_cache[a2];
    float4 k2b = *(const float4*)&k_cache[a2 + 64];
    float4 k3a = *(const float4*)&k_cache[a3];
    float4 k3b = *(const float4*)&k_cache[a3 + 64];
#define SCORE4(ka, kb, jtok)                                       \
    {                                                              \
      float p0 = red16_dpp(dot8(qf0[0], qf1[0], ka, kb));          \
      float p1 = red16_dpp(dot8(qf0[1], qf1[1], ka, kb));          \
      float p2 = red16_dpp(dot8(qf0[2], qf1[2], ka, kb));          \
      float p3 = red16_dpp(dot8(qf0[3], qf1[3], ka, kb));          \
      if (li < 4 && (jtok) < ncache) {                             \
        float x = (li == 0) ? p0 : (li == 1) ? p1 : (li == 2) ? p2 : p3; \
        s_sc[li][jtok] = x;                                        \
      }                                                            \
    }
    SCORE4(k0a, k0b, j_0)
    SCORE4(k1a, k1b, j_1)
    SCORE4(k2a, k2b, j_2)
    SCORE4(k3a, k3b, j_3)
  }
  __syncthreads();

  // softmax partial: wave w handles head w over [0, ntok)
  {
    float m = -3.0e38f;
    for (int t = lane; t < ntok; t += 64) m = fmaxf(m, s_sc[w][t]);
#pragma unroll
    for (int msk = 1; msk < 64; msk <<= 1) m = fmaxf(m, __shfl_xor(m, msk));
    float sum = 0.f;
    for (int t = lane; t < ntok; t += 64) {
      float p = __expf(s_sc[w][t] - m);
      s_sc[w][t] = p;
      sum += p;
    }
#pragma unroll
    for (int msk = 1; msk < 64; msk <<= 1) sum += __shfl_xor(sum, msk);
    if (lane == 0) {
      int part = ((s * NKV + kv) * GRP + w) * NSPLIT + sp;
      mlW[part] = make_float2(m, sum);
    }
  }
  __syncthreads();

  // pass 2: P·V, batch-4 loads then accumulate
  float4 aa0 = {0,0,0,0}, aa1 = {0,0,0,0}, aa2 = {0,0,0,0}, aa3 = {0,0,0,0};
  float4 ab0 = {0,0,0,0}, ab1 = {0,0,0,0}, ab2 = {0,0,0,0}, ab3 = {0,0,0,0};
  for (int j0 = w * 4; j0 < ncache; j0 += 64) {
    ADDR4(j0)
    float4 v0a = *(const float4*)&v_cache[a0];
    float4 v0b = *(const float4*)&v_cache[a0 + 64];
    float4 v1a = *(const float4*)&v_cache[a1];
    float4 v1b = *(const float4*)&v_cache[a1 + 64];
    float4 v2a = *(const float4*)&v_cache[a2];
    float4 v2b = *(const float4*)&v_cache[a2 + 64];
    float4 v3a = *(const float4*)&v_cache[a3];
    float4 v3b = *(const float4*)&v_cache[a3 + 64];
#define PV4(va, vb, jtok)                                          \
    {                                                              \
      bool valid = (jtok) < ncache;                                \
      float p0 = valid ? s_sc[0][jtok] : 0.f;                      \
      float p1 = valid ? s_sc[1][jtok] : 0.f;                      \
      float p2 = valid ? s_sc[2][jtok] : 0.f;                      \
      float p3 = valid ? s_sc[3][jtok] : 0.f;                      \
      aa0.x = fmaf(p0, va.x, aa0.x); aa0.y = fmaf(p0, va.y, aa0.y);\
      aa0.z = fmaf(p0, va.z, aa0.z); aa0.w = fmaf(p0, va.w, aa0.w);\
      ab0.x = fmaf(p0, vb.x, ab0.x); ab0.y = fmaf(p0, vb.y, ab0.y);\
      ab0.z = fmaf(p0, vb.z, ab0.z); ab0.w = fmaf(p0, vb.w, ab0.w);\
      aa1.x = fmaf(p1, va.x, aa1.x); aa1.y = fmaf(p1, va.y, aa1.y);\
      aa1.z = fmaf(p1, va.z, aa1.z); aa1.w = fmaf(p1, va.w, aa1.w);\
      ab1.x = fmaf(p1, vb.x, ab1.x); ab1.y = fmaf(p1, vb.y, ab1.y);\
      ab1.z = fmaf(p1, vb.z, ab1.z); ab1.w = fmaf(p1, vb.w, ab1.w);\
      aa2.x = fmaf(p2, va.x, aa2.x); aa2.y = fmaf(p2, va.y, aa2.y);\
      aa2.z = fmaf(p2, va.z, aa2.z); aa2.w = fmaf(p2, va.w, aa2.w);\
      ab2.x = fmaf(p2, vb.x, ab2.x); ab2.y = fmaf(p2, vb.y, ab2.y);\
      ab2.z = fmaf(p2, vb.z, ab2.z); ab2.w = fmaf(p2, vb.w, ab2.w);\
      aa3.x = fmaf(p3, va.x, aa3.x); aa3.y = fmaf(p3, va.y, aa3.y);\
      aa3.z = fmaf(p3, va.z, aa3.z); aa3.w = fmaf(p3, va.w, aa3.w);\
      ab3.x = fmaf(p3, vb.x, ab3.x); ab3.y = fmaf(p3, vb.y, ab3.y);\
      ab3.z = fmaf(p3, vb.z, ab3.z); ab3.w = fmaf(p3, vb.w, ab3.w);\
    }
    PV4(v0a, v0b, j_0)
    PV4(v1a, v1b, j_1)
    PV4(v2a, v2b, j_2)
    PV4(v3a, v3b, j_3)
  }
  red_sub(aa0); red_sub(aa1); red_sub(aa2); red_sub(aa3);
  red_sub(ab0); red_sub(ab1); red_sub(ab2); red_sub(ab3);
  if (lane < 16) {
    *(float4*)&acc_lds[w][0][li * 4] = aa0;
    *(float4*)&acc_lds[w][1][li * 4] = aa1;
    *(float4*)&acc_lds[w][2][li * 4] = aa2;
    *(float4*)&acc_lds[w][3][li * 4] = aa3;
    *(float4*)&acc_lds[w][0][64 + li * 4] = ab0;
    *(float4*)&acc_lds[w][1][64 + li * 4] = ab1;
    *(float4*)&acc_lds[w][2][64 + li * 4] = ab2;
    *(float4*)&acc_lds[w][3][64 + li * 4] = ab3;
  }
  __syncthreads();

  // epilogue: combine waves, add new-token V, write UNNORMALIZED partial
  {
    const float* vp = v_new + (s * NKV + kv) * HD;
#pragma unroll
    for (int j = tid; j < GRP * HD; j += 256) {
      int h = j >> 7, d = j & 127;
      float o = acc_lds[0][h][d] + acc_lds[1][h][d] + acc_lds[2][h][d] + acc_lds[3][h][d];
      if (has_new) o = fmaf(s_sc[h][ncache], vp[d], o);
      int part = ((s * NKV + kv) * GRP + h) * NSPLIT + sp;
      accW[part * HD + d] = o;
    }
  }
}

// LSE-combine the per-split partials. One wave per (seq, head).
extern "C" __global__ __launch_bounds__(256, 8)
void paged_reduce(const float* __restrict__ accW,
                  const float2* __restrict__ mlW,
                  const int* __restrict__ context_lens,
                  float* __restrict__ out)
{
  const int tid  = threadIdx.x;
  const int lane = tid & 63;
  const int w    = tid >> 6;
  const int idx  = blockIdx.x * 4 + w;   // 0..1023 = (s, h)
  const int s    = idx >> 5;
  const int h    = idx & 31;
  const int kv   = h >> 2, g = h & 3;
  const int ctx  = context_lens[s];
  const int nsp  = (ctx + CHUNK - 1) / CHUNK;
  const int pbase = ((s * NKV + kv) * GRP + g) * NSPLIT;

  float m = -3.0e38f;
  for (int i = 0; i < nsp; ++i) m = fmaxf(m, mlW[pbase + i].x);
  float L = 0.f;
  float2 acc = {0.f, 0.f};
  for (int i = 0; i < nsp; ++i) {
    float2 ml = mlW[pbase + i];
    float sc = __expf(ml.x - m);
    L += ml.y * sc;
    float2 a = *(const float2*)&accW[(pbase + i) * HD + lane * 2];
    acc.x = fmaf(a.x, sc, acc.x);
    acc.y = fmaf(a.y, sc, acc.y);
  }
  float inv = 1.0f / L;
  float2 o = make_float2(acc.x * inv, acc.y * inv);
  *(float2*)&out[(s * NH + h) * HD + lane * 2] = o;
}

extern "C" void kernel_launch(void* const* d_in, const int* in_sizes, int n_in,
                              void* d_out, int out_size, void* d_ws, size_t ws_size,
                              hipStream_t stream) {
  const float* q         = (const float*)d_in[0];
  const float* k_new     = (const float*)d_in[1];
  const float* v_new     = (const float*)d_in[2];
  const float* k_cache   = (const float*)d_in[3];
  const float* v_cache   = (const float*)d_in[4];
  const float* cos_cache = (const float*)d_in[5];
  const float* sin_cache = (const float*)d_in[6];
  const int* block_tables = (const int*)d_in[9];
  const int* context_lens = (const int*)d_in[10];
  float* out = (float*)d_out;

  float*  accW = (float*)d_ws;   // NSEQ*NKV*GRP*NSPLIT*HD floats = 4 MB
  float2* mlW  = (float2*)((char*)d_ws + (size_t)NSEQ * NKV * GRP * NSPLIT * HD * sizeof(float));

  dim3 grid(NKV, NSEQ * NSPLIT);   // y = dense active-split index
  paged_split<<<grid, 256, 0, stream>>>(q, k_new, v_new, k_cache, v_cache,
                                        cos_cache, sin_cache, block_tables,
                                        context_lens, accW, mlW);
  paged_reduce<<<NSEQ * NH / 4, 256, 0, stream>>>(accW, mlW, context_lens, out);
}

// Round 12
// 57.386 us; speedup vs baseline: 1.1917x; 1.0052x over previous
//
#include <hip/hip_runtime.h>

#define NSEQ 32
#define NH 32
#define NKV 8
#define GRP 4
#define HD 128
#define BS 16
#define MAXCTX 2048
#define BPS 128
#define CHUNK 256
#define NSPLIT (MAXCTX / CHUNK)   // 8
#define SCALE 0.08838834764831845f

__device__ __forceinline__ float dot8(float4 qa, float4 qb, float4 ka, float4 kb) {
  float r = qa.x * ka.x;
  r = fmaf(qa.y, ka.y, r);
  r = fmaf(qa.z, ka.z, r);
  r = fmaf(qa.w, ka.w, r);
  r = fmaf(qb.x, kb.x, r);
  r = fmaf(qb.y, kb.y, r);
  r = fmaf(qb.z, kb.z, r);
  r = fmaf(qb.w, kb.w, r);
  return r;
}

// 16-lane sum entirely on the VALU pipe (DPP).
__device__ __forceinline__ float red16_dpp(float x) {
  x += __int_as_float(__builtin_amdgcn_update_dpp(0, __float_as_int(x), 0xB1, 0xF, 0xF, true));
  x += __int_as_float(__builtin_amdgcn_update_dpp(0, __float_as_int(x), 0x4E, 0xF, 0xF, true));
  x += __int_as_float(__builtin_amdgcn_update_dpp(0, __float_as_int(x), 0x141, 0xF, 0xF, true));
  x += __int_as_float(__builtin_amdgcn_update_dpp(0, __float_as_int(x), 0x140, 0xF, 0xF, true));
  return x;
}

__device__ __forceinline__ void red_sub(float4& v) {
  v.x += __shfl_xor(v.x, 16); v.y += __shfl_xor(v.y, 16);
  v.z += __shfl_xor(v.z, 16); v.w += __shfl_xor(v.w, 16);
  v.x += __shfl_xor(v.x, 32); v.y += __shfl_xor(v.y, 32);
  v.z += __shfl_xor(v.z, 32); v.w += __shfl_xor(v.w, 32);
}

// One workgroup per (dense-active-split, kv-head). Grid x = dense split so
// the 8 kv-sibling blocks of a split share bid%8 -> same XCD/L2 -> their
// 8x512B slices of each 4KB token row merge into full-row DRAM streams.
extern "C" __global__ __launch_bounds__(256, 4)
void paged_split(const float* __restrict__ q,
                 const float* __restrict__ k_new,
                 const float* __restrict__ v_new,
                 const float* __restrict__ k_cache,
                 const float* __restrict__ v_cache,
                 const float* __restrict__ cos_cache,
                 const float* __restrict__ sin_cache,
                 const int* __restrict__ block_tables,
                 const int* __restrict__ context_lens,
                 float* __restrict__ accW,
                 float2* __restrict__ mlW)
{
  const int kv = blockIdx.y;   // 0..7  (slow grid dim)
  // ---- dense remap: blockIdx.x -> (s, sp), wave-uniform scan ----
  int s = -1, sp = blockIdx.x;
  for (int i = 0; i < NSEQ; ++i) {
    int ns = (context_lens[i] + CHUNK - 1) / CHUNK;
    if (sp < ns) { s = i; break; }
    sp -= ns;
  }
  if (s < 0) return;

  const int ctx = context_lens[s];
  const int t0  = sp * CHUNK;
  const int tend = min(t0 + CHUNK, ctx);
  const int ntok = tend - t0;
  const int pos  = ctx - 1;
  const bool has_new = (pos >= t0) && (pos < tend);
  const int ncache = has_new ? (pos - t0) : ntok;

  const int tid  = threadIdx.x;
  const int lane = tid & 63;
  const int w    = tid >> 6;
  const int sub  = lane >> 4;
  const int li   = lane & 15;

  __shared__ float cs_lds[64];
  __shared__ float sn_lds[64];
  __shared__ float qrot[GRP * HD];       // 2 KB
  __shared__ float krot[HD];             // 512 B
  __shared__ int   bt[CHUNK / BS];       // 16 entries
  __shared__ float s_sc[GRP][CHUNK];     // 4 KB (scores -> p)
  __shared__ float acc_lds[4][GRP][HD];  // 8 KB

  if (tid < 64) {
    cs_lds[tid] = cos_cache[pos * 64 + tid];
    sn_lds[tid] = sin_cache[pos * 64 + tid];
  }
  if (tid >= 192 && tid < 192 + CHUNK / BS)
    bt[tid - 192] = block_tables[s * BPS + (t0 >> 4) + (tid - 192)];
  __syncthreads();

  // RoPE q (SCALE folded in) into LDS
  {
    const float* qp = q + (s * NH + kv * GRP) * HD;
#pragma unroll
    for (int j = tid; j < GRP * HD; j += 256) {
      int h = j >> 7, d = j & 127;
      float r;
      if (d < 64) r = qp[h * HD + d] * cs_lds[d] - qp[h * HD + d + 64] * sn_lds[d];
      else        r = qp[h * HD + d] * cs_lds[d - 64] + qp[h * HD + d - 64] * sn_lds[d - 64];
      qrot[j] = r * SCALE;
    }
  }
  if (has_new && tid < 128) {
    const float* kp = k_new + (s * NKV + kv) * HD;
    int d = tid;
    float r;
    if (d < 64) r = kp[d] * cs_lds[d] - kp[d + 64] * sn_lds[d];
    else        r = kp[d] * cs_lds[d - 64] + kp[d - 64] * sn_lds[d - 64];
    krot[d] = r;
  }
  __syncthreads();

  float4 qf0[GRP], qf1[GRP];
#pragma unroll
  for (int h = 0; h < GRP; ++h) {
    qf0[h] = *(const float4*)&qrot[h * HD + li * 4];
    qf1[h] = *(const float4*)&qrot[h * HD + 64 + li * 4];
  }

  // new-token score (local index == ncache), wave 0
  if (w == 0 && has_new) {
    float4 ka = *(const float4*)&krot[li * 4];
    float4 kb = *(const float4*)&krot[64 + li * 4];
    float p0 = red16_dpp(dot8(qf0[0], qf1[0], ka, kb));
    float p1 = red16_dpp(dot8(qf0[1], qf1[1], ka, kb));
    float p2 = red16_dpp(dot8(qf0[2], qf1[2], ka, kb));
    float p3 = red16_dpp(dot8(qf0[3], qf1[3], ka, kb));
    if (lane == 0) {
      s_sc[0][ncache] = p0; s_sc[1][ncache] = p1;
      s_sc[2][ncache] = p2; s_sc[3][ncache] = p3;
    }
  }

  // addresses for 4 token-groups starting at j0 (this lane handles j0+sub+16u)
#define ADDR4(j0)                                                        \
  int j_0 = (j0) + sub,      j_1 = j_0 + 16, j_2 = j_0 + 32, j_3 = j_0 + 48; \
  int jc0 = j_0 < ncache ? j_0 : ncache - 1;                             \
  int jc1 = j_1 < ncache ? j_1 : ncache - 1;                             \
  int jc2 = j_2 < ncache ? j_2 : ncache - 1;                             \
  int jc3 = j_3 < ncache ? j_3 : ncache - 1;                             \
  int a0 = ((bt[jc0 >> 4] * BS + (jc0 & 15)) * NKV + kv) * HD + li * 4;  \
  int a1 = ((bt[jc1 >> 4] * BS + (jc1 & 15)) * NKV + kv) * HD + li * 4;  \
  int a2 = ((bt[jc2 >> 4] * BS + (jc2 & 15)) * NKV + kv) * HD + li * 4;  \
  int a3 = ((bt[jc3 >> 4] * BS + (jc3 & 15)) * NKV + kv) * HD + li * 4;

  // pass 1: QK^T, batch-4 loads then compute
  for (int j0 = w * 4; j0 < ncache; j0 += 64) {
    ADDR4(j0)
    float4 k0a = *(const float4*)&k_cache[a0];
    float4 k0b = *(const float4*)&k_cache[a0 + 64];
    float4 k1a = *(const float4*)&k_cache[a1];
    float4 k1b = *(const float4*)&k_cache[a1 + 64];
    float4 k2a = *(const float4*)&k_cache[a2];
    float4 k2b = *(const float4*)&k_cache[a2 + 64];
    float4 k3a = *(const float4*)&k_cache[a3];
    float4 k3b = *(const float4*)&k_cache[a3 + 64];
#define SCORE4(ka, kb, jtok)                                       \
    {                                                              \
      float p0 = red16_dpp(dot8(qf0[0], qf1[0], ka, kb));          \
      float p1 = red16_dpp(dot8(qf0[1], qf1[1], ka, kb));          \
      float p2 = red16_dpp(dot8(qf0[2], qf1[2], ka, kb));          \
      float p3 = red16_dpp(dot8(qf0[3], qf1[3], ka, kb));          \
      if (li < 4 && (jtok) < ncache) {                             \
        float x = (li == 0) ? p0 : (li == 1) ? p1 : (li == 2) ? p2 : p3; \
        s_sc[li][jtok] = x;                                        \
      }                                                            \
    }
    SCORE4(k0a, k0b, j_0)
    SCORE4(k1a, k1b, j_1)
    SCORE4(k2a, k2b, j_2)
    SCORE4(k3a, k3b, j_3)
  }
  __syncthreads();

  // softmax partial: wave w handles head w over [0, ntok)
  {
    float m = -3.0e38f;
    for (int t = lane; t < ntok; t += 64) m = fmaxf(m, s_sc[w][t]);
#pragma unroll
    for (int msk = 1; msk < 64; msk <<= 1) m = fmaxf(m, __shfl_xor(m, msk));
    float sum = 0.f;
    for (int t = lane; t < ntok; t += 64) {
      float p = __expf(s_sc[w][t] - m);
      s_sc[w][t] = p;
      sum += p;
    }
#pragma unroll
    for (int msk = 1; msk < 64; msk <<= 1) sum += __shfl_xor(sum, msk);
    if (lane == 0) {
      int part = ((s * NKV + kv) * GRP + w) * NSPLIT + sp;
      mlW[part] = make_float2(m, sum);
    }
  }
  __syncthreads();

  // pass 2: P·V, batch-4 loads then accumulate
  float4 aa0 = {0,0,0,0}, aa1 = {0,0,0,0}, aa2 = {0,0,0,0}, aa3 = {0,0,0,0};
  float4 ab0 = {0,0,0,0}, ab1 = {0,0,0,0}, ab2 = {0,0,0,0}, ab3 = {0,0,0,0};
  for (int j0 = w * 4; j0 < ncache; j0 += 64) {
    ADDR4(j0)
    float4 v0a = *(const float4*)&v_cache[a0];
    float4 v0b = *(const float4*)&v_cache[a0 + 64];
    float4 v1a = *(const float4*)&v_cache[a1];
    float4 v1b = *(const float4*)&v_cache[a1 + 64];
    float4 v2a = *(const float4*)&v_cache[a2];
    float4 v2b = *(const float4*)&v_cache[a2 + 64];
    float4 v3a = *(const float4*)&v_cache[a3];
    float4 v3b = *(const float4*)&v_cache[a3 + 64];
#define PV4(va, vb, jtok)                                          \
    {                                                              \
      bool valid = (jtok) < ncache;                                \
      float p0 = valid ? s_sc[0][jtok] : 0.f;                      \
      float p1 = valid ? s_sc[1][jtok] : 0.f;                      \
      float p2 = valid ? s_sc[2][jtok] : 0.f;                      \
      float p3 = valid ? s_sc[3][jtok] : 0.f;                      \
      aa0.x = fmaf(p0, va.x, aa0.x); aa0.y = fmaf(p0, va.y, aa0.y);\
      aa0.z = fmaf(p0, va.z, aa0.z); aa0.w = fmaf(p0, va.w, aa0.w);\
      ab0.x = fmaf(p0, vb.x, ab0.x); ab0.y = fmaf(p0, vb.y, ab0.y);\
      ab0.z = fmaf(p0, vb.z, ab0.z); ab0.w = fmaf(p0, vb.w, ab0.w);\
      aa1.x = fmaf(p1, va.x, aa1.x); aa1.y = fmaf(p1, va.y, aa1.y);\
      aa1.z = fmaf(p1, va.z, aa1.z); aa1.w = fmaf(p1, va.w, aa1.w);\
      ab1.x = fmaf(p1, vb.x, ab1.x); ab1.y = fmaf(p1, vb.y, ab1.y);\
      ab1.z = fmaf(p1, vb.z, ab1.z); ab1.w = fmaf(p1, vb.w, ab1.w);\
      aa2.x = fmaf(p2, va.x, aa2.x); aa2.y = fmaf(p2, va.y, aa2.y);\
      aa2.z = fmaf(p2, va.z, aa2.z); aa2.w = fmaf(p2, va.w, aa2.w);\
      ab2.x = fmaf(p2, vb.x, ab2.x); ab2.y = fmaf(p2, vb.y, ab2.y);\
      ab2.z = fmaf(p2, vb.z, ab2.z); ab2.w = fmaf(p2, vb.w, ab2.w);\
      aa3.x = fmaf(p3, va.x, aa3.x); aa3.y = fmaf(p3, va.y, aa3.y);\
      aa3.z = fmaf(p3, va.z, aa3.z); aa3.w = fmaf(p3, va.w, aa3.w);\
      ab3.x = fmaf(p3, vb.x, ab3.x); ab3.y = fmaf(p3, vb.y, ab3.y);\
      ab3.z = fmaf(p3, vb.z, ab3.z); ab3.w = fmaf(p3, vb.w, ab3.w);\
    }
    PV4(v0a, v0b, j_0)
    PV4(v1a, v1b, j_1)
    PV4(v2a, v2b, j_2)
    PV4(v3a, v3b, j_3)
  }
  red_sub(aa0); red_sub(aa1); red_sub(aa2); red_sub(aa3);
  red_sub(ab0); red_sub(ab1); red_sub(ab2); red_sub(ab3);
  if (lane < 16) {
    *(float4*)&acc_lds[w][0][li * 4] = aa0;
    *(float4*)&acc_lds[w][1][li * 4] = aa1;
    *(float4*)&acc_lds[w][2][li * 4] = aa2;
    *(float4*)&acc_lds[w][3][li * 4] = aa3;
    *(float4*)&acc_lds[w][0][64 + li * 4] = ab0;
    *(float4*)&acc_lds[w][1][64 + li * 4] = ab1;
    *(float4*)&acc_lds[w][2][64 + li * 4] = ab2;
    *(float4*)&acc_lds[w][3][64 + li * 4] = ab3;
  }
  __syncthreads();

  // epilogue: combine waves, add new-token V, write UNNORMALIZED partial
  {
    const float* vp = v_new + (s * NKV + kv) * HD;
#pragma unroll
    for (int j = tid; j < GRP * HD; j += 256) {
      int h = j >> 7, d = j & 127;
      float o = acc_lds[0][h][d] + acc_lds[1][h][d] + acc_lds[2][h][d] + acc_lds[3][h][d];
      if (has_new) o = fmaf(s_sc[h][ncache], vp[d], o);
      int part = ((s * NKV + kv) * GRP + h) * NSPLIT + sp;
      accW[part * HD + d] = o;
    }
  }
}

// LSE-combine the per-split partials. One wave per (seq, head).
extern "C" __global__ __launch_bounds__(256, 8)
void paged_reduce(const float* __restrict__ accW,
                  const float2* __restrict__ mlW,
                  const int* __restrict__ context_lens,
                  float* __restrict__ out)
{
  const int tid  = threadIdx.x;
  const int lane = tid & 63;
  const int w    = tid >> 6;
  const int idx  = blockIdx.x * 4 + w;   // 0..1023 = (s, h)
  const int s    = idx >> 5;
  const int h    = idx & 31;
  const int kv   = h >> 2, g = h & 3;
  const int ctx  = context_lens[s];
  const int nsp  = (ctx + CHUNK - 1) / CHUNK;
  const int pbase = ((s * NKV + kv) * GRP + g) * NSPLIT;

  float m = -3.0e38f;
  for (int i = 0; i < nsp; ++i) m = fmaxf(m, mlW[pbase + i].x);
  float L = 0.f;
  float2 acc = {0.f, 0.f};
  for (int i = 0; i < nsp; ++i) {
    float2 ml = mlW[pbase + i];
    float sc = __expf(ml.x - m);
    L += ml.y * sc;
    float2 a = *(const float2*)&accW[(pbase + i) * HD + lane * 2];
    acc.x = fmaf(a.x, sc, acc.x);
    acc.y = fmaf(a.y, sc, acc.y);
  }
  float inv = 1.0f / L;
  float2 o = make_float2(acc.x * inv, acc.y * inv);
  *(float2*)&out[(s * NH + h) * HD + lane * 2] = o;
}

extern "C" void kernel_launch(void* const* d_in, const int* in_sizes, int n_in,
                              void* d_out, int out_size, void* d_ws, size_t ws_size,
                              hipStream_t stream) {
  const float* q         = (const float*)d_in[0];
  const float* k_new     = (const float*)d_in[1];
  const float* v_new     = (const float*)d_in[2];
  const float* k_cache   = (const float*)d_in[3];
  const float* v_cache   = (const float*)d_in[4];
  const float* cos_cache = (const float*)d_in[5];
  const float* sin_cache = (const float*)d_in[6];
  const int* block_tables = (const int*)d_in[9];
  const int* context_lens = (const int*)d_in[10];
  float* out = (float*)d_out;

  float*  accW = (float*)d_ws;   // NSEQ*NKV*GRP*NSPLIT*HD floats = 4 MB
  float2* mlW  = (float2*)((char*)d_ws + (size_t)NSEQ * NKV * GRP * NSPLIT * HD * sizeof(float));

  // x = dense split (multiple of 8) so the 8 kv-siblings of a split share
  // bid%8 -> same XCD -> L2-coalesced full-row reads of the 4KB token rows.
  dim3 grid(NSEQ * NSPLIT, NKV);
  paged_split<<<grid, 256, 0, stream>>>(q, k_new, v_new, k_cache, v_cache,
                                        cos_cache, sin_cache, block_tables,
                                        context_lens, accW, mlW);
  paged_reduce<<<NSEQ * NH / 4, 256, 0, stream>>>(accW, mlW, context_lens, out);
}